// Round 1
// baseline (230.660 us; speedup 1.0000x reference)
//
#include <hip/hip_runtime.h>
#include <math.h>

// DKVMN forward: B=128, S=200, DK=128, DV=64, NUM_Q=10000
// Kernel A (wea): per-token w=softmax(k@Mk^T), e=sigmoid(v@eW+eb), a=tanh(v@aW+ab)
// Kernel B (scan): per (batch, column-half) sequential memory update, read extraction
// Kernel C (out):  f=tanh([read|k]@fW+fb), p=sigmoid(f@pW+pb)

__device__ __forceinline__ float sigm(float x) { return 1.0f / (1.0f + __expf(-x)); }

// ---------------------------------------------------------------------------
// Kernel A: 16 rows (tokens) per 256-thread block. 1600 blocks.
// ---------------------------------------------------------------------------
__global__ __launch_bounds__(256) void wea_kernel(
    const int* __restrict__ qseq, const int* __restrict__ cseq,
    const float* __restrict__ k_emb, const float* __restrict__ v_emb,
    const float* __restrict__ Mk,
    const float* __restrict__ eW, const float* __restrict__ eb,
    const float* __restrict__ aW, const float* __restrict__ ab,
    int num_q,
    float* __restrict__ w_ws, float* __restrict__ e_ws, float* __restrict__ a_ws)
{
    __shared__ float k_lds[16][128];
    __shared__ float v_lds[16][128];
    __shared__ float mk_lds[64 * 130];   // padded stride 130 -> conflict-light
    __shared__ int qi[16], xi[16];

    const int t  = threadIdx.x;
    const int R0 = blockIdx.x * 16;

    if (t < 16) {
        const int R = R0 + t;
        const int q = qseq[R];
        const int c = cseq[R];
        qi[t] = q;
        xi[t] = q + num_q * c;
    }
    // stage Mk (64x128) into padded LDS, float4 loads
    for (int idx = t; idx < 2048; idx += 256) {
        const int dv = idx >> 5, i4 = idx & 31;
        const float4 m4 = *(const float4*)(Mk + dv * 128 + i4 * 4);
        float* d = &mk_lds[dv * 130 + i4 * 4];
        d[0] = m4.x; d[1] = m4.y; d[2] = m4.z; d[3] = m4.w;
    }
    __syncthreads();
    // gather k,v rows (16 x 128 each) as float4
    for (int idx = t; idx < 512; idx += 256) {
        const int r = idx >> 5, i4 = idx & 31;
        *(float4*)&k_lds[r][i4 * 4] = *(const float4*)(k_emb + (size_t)qi[r] * 128 + i4 * 4);
        *(float4*)&v_lds[r][i4 * 4] = *(const float4*)(v_emb + (size_t)xi[r] * 128 + i4 * 4);
    }
    __syncthreads();

    // ---- w: logits + softmax. lane = dv (64), wave = row group (4 rows each) ----
    {
        const int dv = t & 63;
        const int wv = t >> 6;
        const float* mkrow = &mk_lds[dv * 130];
        #pragma unroll
        for (int rr = 0; rr < 4; ++rr) {
            const int r = wv * 4 + rr;
            float acc = 0.f;
            #pragma unroll 8
            for (int i = 0; i < 128; i += 2) {
                const float2 m2 = *(const float2*)&mkrow[i];
                const float2 k2 = *(const float2*)&k_lds[r][i];
                acc = fmaf(k2.x, m2.x, acc);
                acc = fmaf(k2.y, m2.y, acc);
            }
            float m = acc;
            #pragma unroll
            for (int o = 32; o; o >>= 1) m = fmaxf(m, __shfl_xor(m, o));
            const float ex = __expf(acc - m);
            float sm = ex;
            #pragma unroll
            for (int o = 32; o; o >>= 1) sm += __shfl_xor(sm, o);
            const int R = R0 + r;
            w_ws[(size_t)R * 64 + dv] = ex / sm;
        }
    }

    // ---- e, a: thread = (col j, half h); each computes 8 full rows ----
    {
        const int j = t & 127;
        const int h = t >> 7;
        float acc_e[8], acc_a[8];
        #pragma unroll
        for (int r = 0; r < 8; ++r) { acc_e[r] = 0.f; acc_a[r] = 0.f; }
        for (int i0 = 0; i0 < 128; i0 += 4) {
            float ew[4], aw[4];
            #pragma unroll
            for (int ii = 0; ii < 4; ++ii) {
                ew[ii] = eW[(i0 + ii) * 128 + j];
                aw[ii] = aW[(i0 + ii) * 128 + j];
            }
            #pragma unroll
            for (int r = 0; r < 8; ++r) {
                const float4 v4 = *(const float4*)&v_lds[h * 8 + r][i0];
                acc_e[r] = fmaf(v4.x, ew[0], acc_e[r]);
                acc_e[r] = fmaf(v4.y, ew[1], acc_e[r]);
                acc_e[r] = fmaf(v4.z, ew[2], acc_e[r]);
                acc_e[r] = fmaf(v4.w, ew[3], acc_e[r]);
                acc_a[r] = fmaf(v4.x, aw[0], acc_a[r]);
                acc_a[r] = fmaf(v4.y, aw[1], acc_a[r]);
                acc_a[r] = fmaf(v4.z, aw[2], acc_a[r]);
                acc_a[r] = fmaf(v4.w, aw[3], acc_a[r]);
            }
        }
        const float ebj = eb[j], abj = ab[j];
        const int jh = j >> 6, jj = j & 63;
        #pragma unroll
        for (int r = 0; r < 8; ++r) {
            const int R = R0 + h * 8 + r;
            const int b = R / 200, s = R % 200;
            // layout [b*2+jh][s][jj] so the scan kernel reads its half contiguously
            const size_t off = ((size_t)(b * 2 + jh) * 200 + s) * 64 + jj;
            e_ws[off] = sigm(acc_e[r] + ebj);
            a_ws[off] = tanhf(acc_a[r] + abj);
        }
    }
}

// ---------------------------------------------------------------------------
// Kernel B: scan. One wave per block; block = (batch, column-half). 256 blocks.
// Thread owns column j: Mv[0..63][j] in registers. Chunked (8-step) LDS
// double-buffer prefetch of w/e/a.
// ---------------------------------------------------------------------------
__global__ __launch_bounds__(64) void scan_kernel(
    const float* __restrict__ Mv0,
    const float* __restrict__ w_ws, const float* __restrict__ e_ws,
    const float* __restrict__ a_ws, float* __restrict__ reads_ws)
{
    const int lane = threadIdx.x;
    const int ch   = blockIdx.x & 1;
    const int b    = blockIdx.x >> 1;
    const int j    = ch * 64 + lane;

    float Mv[64];
    #pragma unroll
    for (int v = 0; v < 64; ++v) Mv[v] = Mv0[v * 128 + j];

    __shared__ float wb[2][512];
    __shared__ float ebuf[2][512];
    __shared__ float abuf[2][512];

    const float4* wp = (const float4*)(w_ws + (size_t)b * 200 * 64);
    const float4* ep = (const float4*)(e_ws + (size_t)(b * 2 + ch) * 200 * 64);
    const float4* ap = (const float4*)(a_ws + (size_t)(b * 2 + ch) * 200 * 64);
    float* rp = reads_ws + (size_t)b * 200 * 128 + j;

    // prologue: chunk 0 -> buf 0
    float4 pw0 = wp[lane * 2], pw1 = wp[lane * 2 + 1];
    float4 pe0 = ep[lane * 2], pe1 = ep[lane * 2 + 1];
    float4 pa0 = ap[lane * 2], pa1 = ap[lane * 2 + 1];
    ((float4*)wb[0])[lane * 2] = pw0;   ((float4*)wb[0])[lane * 2 + 1] = pw1;
    ((float4*)ebuf[0])[lane * 2] = pe0; ((float4*)ebuf[0])[lane * 2 + 1] = pe1;
    ((float4*)abuf[0])[lane * 2] = pa0; ((float4*)abuf[0])[lane * 2 + 1] = pa1;
    __syncthreads();

    int cb = 0;
    for (int c = 0; c < 25; ++c) {
        if (c < 24) {   // issue next-chunk loads (hidden under this chunk's compute)
            const int o = (c + 1) * 128;
            pw0 = wp[o + lane * 2]; pw1 = wp[o + lane * 2 + 1];
            pe0 = ep[o + lane * 2]; pe1 = ep[o + lane * 2 + 1];
            pa0 = ap[o + lane * 2]; pa1 = ap[o + lane * 2 + 1];
        }
        for (int st = 0; st < 8; ++st) {
            const float e_j = ebuf[cb][st * 64 + lane];
            const float a_j = abuf[cb][st * 64 + lane];
            const float* wrow = &wb[cb][st * 64];
            float r0 = 0.f, r1 = 0.f, r2 = 0.f, r3 = 0.f;
            #pragma unroll
            for (int v4 = 0; v4 < 16; ++v4) {
                const float4 w4 = *(const float4*)&wrow[v4 * 4];  // LDS broadcast
                const int v = v4 * 4;
                r0 = fmaf(w4.x, Mv[v + 0], r0);
                Mv[v + 0] = fmaf(w4.x, fmaf(-Mv[v + 0], e_j, a_j), Mv[v + 0]);
                r1 = fmaf(w4.y, Mv[v + 1], r1);
                Mv[v + 1] = fmaf(w4.y, fmaf(-Mv[v + 1], e_j, a_j), Mv[v + 1]);
                r2 = fmaf(w4.z, Mv[v + 2], r2);
                Mv[v + 2] = fmaf(w4.z, fmaf(-Mv[v + 2], e_j, a_j), Mv[v + 2]);
                r3 = fmaf(w4.w, Mv[v + 3], r3);
                Mv[v + 3] = fmaf(w4.w, fmaf(-Mv[v + 3], e_j, a_j), Mv[v + 3]);
            }
            rp[(size_t)(c * 8 + st) * 128] = (r0 + r1) + (r2 + r3);
        }
        __syncthreads();
        if (c < 24) {
            const int nb = cb ^ 1;
            ((float4*)wb[nb])[lane * 2] = pw0;   ((float4*)wb[nb])[lane * 2 + 1] = pw1;
            ((float4*)ebuf[nb])[lane * 2] = pe0; ((float4*)ebuf[nb])[lane * 2 + 1] = pe1;
            ((float4*)abuf[nb])[lane * 2] = pa0; ((float4*)abuf[nb])[lane * 2 + 1] = pa1;
        }
        __syncthreads();
        cb ^= 1;
    }
}

// ---------------------------------------------------------------------------
// Kernel C: output head. 16 rows per 256-thread block. 1600 blocks.
// ---------------------------------------------------------------------------
__global__ __launch_bounds__(256) void out_kernel(
    const int* __restrict__ qseq, const float* __restrict__ k_emb,
    const float* __restrict__ reads_ws,
    const float* __restrict__ fW, const float* __restrict__ fb,
    const float* __restrict__ pW, const float* __restrict__ pb,
    float* __restrict__ out)
{
    __shared__ float in_lds[16][256];
    __shared__ float red[16][128];
    __shared__ int qi[16];
    const int t  = threadIdx.x;
    const int R0 = blockIdx.x * 16;
    if (t < 16) qi[t] = qseq[R0 + t];
    __syncthreads();
    for (int idx = t; idx < 512; idx += 256) {
        const int r = idx >> 5, i4 = idx & 31;
        *(float4*)&in_lds[r][i4 * 4]       = *(const float4*)(reads_ws + (size_t)(R0 + r) * 128 + i4 * 4);
        *(float4*)&in_lds[r][128 + i4 * 4] = *(const float4*)(k_emb + (size_t)qi[r] * 128 + i4 * 4);
    }
    __syncthreads();
    const int j = t & 127;
    const int h = t >> 7;
    float acc[8];
    #pragma unroll
    for (int r = 0; r < 8; ++r) acc[r] = 0.f;
    for (int i0 = 0; i0 < 256; i0 += 4) {
        float fw[4];
        #pragma unroll
        for (int ii = 0; ii < 4; ++ii) fw[ii] = fW[(i0 + ii) * 128 + j];
        #pragma unroll
        for (int r = 0; r < 8; ++r) {
            const float4 v4 = *(const float4*)&in_lds[h * 8 + r][i0];
            acc[r] = fmaf(v4.x, fw[0], acc[r]);
            acc[r] = fmaf(v4.y, fw[1], acc[r]);
            acc[r] = fmaf(v4.z, fw[2], acc[r]);
            acc[r] = fmaf(v4.w, fw[3], acc[r]);
        }
    }
    const float fbj = fb[j], pwj = pW[j];
    #pragma unroll
    for (int r = 0; r < 8; ++r) {
        red[h * 8 + r][j] = tanhf(acc[r] + fbj) * pwj;
    }
    __syncthreads();
    if (t < 16) {
        float s = 0.f;
        const float4* p = (const float4*)red[t];
        #pragma unroll 8
        for (int k4 = 0; k4 < 32; ++k4) {
            const float4 x = p[k4];
            s += (x.x + x.y) + (x.z + x.w);
        }
        out[R0 + t] = sigm(s + pb[0]);
    }
}

// ---------------------------------------------------------------------------
extern "C" void kernel_launch(void* const* d_in, const int* in_sizes, int n_in,
                              void* d_out, int out_size, void* d_ws, size_t ws_size,
                              hipStream_t stream)
{
    const int*   qseq  = (const int*)d_in[0];
    const int*   cseq  = (const int*)d_in[1];
    const float* k_emb = (const float*)d_in[2];
    const float* v_emb = (const float*)d_in[3];
    const float* Mk    = (const float*)d_in[4];
    const float* Mv0   = (const float*)d_in[5];
    const float* fW    = (const float*)d_in[6];
    const float* fb    = (const float*)d_in[7];
    const float* eW    = (const float*)d_in[8];
    const float* eb    = (const float*)d_in[9];
    const float* aW    = (const float*)d_in[10];
    const float* ab    = (const float*)d_in[11];
    const float* pW    = (const float*)d_in[12];
    const float* pb    = (const float*)d_in[13];
    const int num_q = in_sizes[2] / 128;

    float* ws = (float*)d_ws;
    float* w_ws     = ws;                         // 128*200*64   = 1,638,400 f
    float* e_ws     = w_ws + (size_t)128 * 200 * 64;   // 128*200*128
    float* a_ws     = e_ws + (size_t)128 * 200 * 128;  // 128*200*128
    float* reads_ws = a_ws + (size_t)128 * 200 * 128;  // 128*200*128
    // total 11,468,800 floats = 45.9 MB of d_ws

    wea_kernel<<<1600, 256, 0, stream>>>(qseq, cseq, k_emb, v_emb, Mk,
                                         eW, eb, aW, ab, num_q,
                                         w_ws, e_ws, a_ws);
    scan_kernel<<<256, 64, 0, stream>>>(Mv0, w_ws, e_ws, a_ws, reads_ws);
    out_kernel<<<1600, 256, 0, stream>>>(qseq, k_emb, reads_ws, fW, fb, pW, pb,
                                         (float*)d_out);
}

// Round 2
// 159.591 us; speedup vs baseline: 1.4453x; 1.4453x over previous
//
#include <hip/hip_runtime.h>
#include <math.h>

// DKVMN forward: B=128, S=200, DK=128, DV=64, NUM_Q=10000
// Kernel A (wea): per-token w=softmax(k@Mk^T), e=sigmoid(v@eW+eb), a=tanh(v@aW+ab)
// Kernel B (scan): per (batch, column-half) sequential memory update, read extraction
//                  v-dimension split across 4 waves (16 slots each), LDS reduction
// Kernel C (out):  f=tanh([read|k]@fW+fb), p=sigmoid(f@pW+pb)

__device__ __forceinline__ float sigm(float x) { return 1.0f / (1.0f + __expf(-x)); }

// ---------------------------------------------------------------------------
// Kernel A: 16 rows (tokens) per 256-thread block. 1600 blocks.
// ---------------------------------------------------------------------------
__global__ __launch_bounds__(256) void wea_kernel(
    const int* __restrict__ qseq, const int* __restrict__ cseq,
    const float* __restrict__ k_emb, const float* __restrict__ v_emb,
    const float* __restrict__ Mk,
    const float* __restrict__ eW, const float* __restrict__ eb,
    const float* __restrict__ aW, const float* __restrict__ ab,
    int num_q,
    float* __restrict__ w_ws, float* __restrict__ e_ws, float* __restrict__ a_ws)
{
    __shared__ float k_lds[16][128];
    __shared__ float v_lds[16][128];
    __shared__ float mk_lds[64 * 130];   // padded stride 130 -> conflict-light
    __shared__ int qi[16], xi[16];

    const int t  = threadIdx.x;
    const int R0 = blockIdx.x * 16;

    if (t < 16) {
        const int R = R0 + t;
        const int q = qseq[R];
        const int c = cseq[R];
        qi[t] = q;
        xi[t] = q + num_q * c;
    }
    // stage Mk (64x128) into padded LDS, float4 loads
    for (int idx = t; idx < 2048; idx += 256) {
        const int dv = idx >> 5, i4 = idx & 31;
        const float4 m4 = *(const float4*)(Mk + dv * 128 + i4 * 4);
        float* d = &mk_lds[dv * 130 + i4 * 4];
        d[0] = m4.x; d[1] = m4.y; d[2] = m4.z; d[3] = m4.w;
    }
    __syncthreads();
    // gather k,v rows (16 x 128 each) as float4
    for (int idx = t; idx < 512; idx += 256) {
        const int r = idx >> 5, i4 = idx & 31;
        *(float4*)&k_lds[r][i4 * 4] = *(const float4*)(k_emb + (size_t)qi[r] * 128 + i4 * 4);
        *(float4*)&v_lds[r][i4 * 4] = *(const float4*)(v_emb + (size_t)xi[r] * 128 + i4 * 4);
    }
    __syncthreads();

    // ---- w: logits + softmax. lane = dv (64), wave = row group (4 rows each) ----
    {
        const int dv = t & 63;
        const int wv = t >> 6;
        const float* mkrow = &mk_lds[dv * 130];
        #pragma unroll
        for (int rr = 0; rr < 4; ++rr) {
            const int r = wv * 4 + rr;
            float acc = 0.f;
            #pragma unroll 8
            for (int i = 0; i < 128; i += 2) {
                const float2 m2 = *(const float2*)&mkrow[i];
                const float2 k2 = *(const float2*)&k_lds[r][i];
                acc = fmaf(k2.x, m2.x, acc);
                acc = fmaf(k2.y, m2.y, acc);
            }
            float m = acc;
            #pragma unroll
            for (int o = 32; o; o >>= 1) m = fmaxf(m, __shfl_xor(m, o));
            const float ex = __expf(acc - m);
            float sm = ex;
            #pragma unroll
            for (int o = 32; o; o >>= 1) sm += __shfl_xor(sm, o);
            const int R = R0 + r;
            w_ws[(size_t)R * 64 + dv] = ex / sm;
        }
    }

    // ---- e, a: thread = (col j, half h); each computes 8 full rows ----
    {
        const int j = t & 127;
        const int h = t >> 7;
        float acc_e[8], acc_a[8];
        #pragma unroll
        for (int r = 0; r < 8; ++r) { acc_e[r] = 0.f; acc_a[r] = 0.f; }
        for (int i0 = 0; i0 < 128; i0 += 4) {
            float ew[4], aw[4];
            #pragma unroll
            for (int ii = 0; ii < 4; ++ii) {
                ew[ii] = eW[(i0 + ii) * 128 + j];
                aw[ii] = aW[(i0 + ii) * 128 + j];
            }
            #pragma unroll
            for (int r = 0; r < 8; ++r) {
                const float4 v4 = *(const float4*)&v_lds[h * 8 + r][i0];
                acc_e[r] = fmaf(v4.x, ew[0], acc_e[r]);
                acc_e[r] = fmaf(v4.y, ew[1], acc_e[r]);
                acc_e[r] = fmaf(v4.z, ew[2], acc_e[r]);
                acc_e[r] = fmaf(v4.w, ew[3], acc_e[r]);
                acc_a[r] = fmaf(v4.x, aw[0], acc_a[r]);
                acc_a[r] = fmaf(v4.y, aw[1], acc_a[r]);
                acc_a[r] = fmaf(v4.z, aw[2], acc_a[r]);
                acc_a[r] = fmaf(v4.w, aw[3], acc_a[r]);
            }
        }
        const float ebj = eb[j], abj = ab[j];
        const int jh = j >> 6, jj = j & 63;
        #pragma unroll
        for (int r = 0; r < 8; ++r) {
            const int R = R0 + h * 8 + r;
            const int b = R / 200, s = R % 200;
            // layout [b*2+jh][s][jj] so the scan kernel reads its half contiguously
            const size_t off = ((size_t)(b * 2 + jh) * 200 + s) * 64 + jj;
            e_ws[off] = sigm(acc_e[r] + ebj);
            a_ws[off] = tanhf(acc_a[r] + abj);
        }
    }
}

// ---------------------------------------------------------------------------
// Kernel B: scan. Block = (batch, column-half), 256 threads = 4 waves.
// Wave wv owns v-slots [wv*16, wv*16+16); thread (wv, lane) keeps
// Mv[wv*16+i][j=ch*64+lane] in 16 registers. Per step: partial read (16 FMA)
// + update (32 FMA), 4-way cross-wave reduction via double-buffered LDS
// partials, exactly one __syncthreads per step. Chunked (8-step) LDS
// double-buffer staging of w/e/a, writes folded into last step of chunk.
// ---------------------------------------------------------------------------
__global__ __launch_bounds__(256) void scan_kernel(
    const float* __restrict__ Mv0,
    const float* __restrict__ w_ws, const float* __restrict__ e_ws,
    const float* __restrict__ a_ws, float* __restrict__ reads_ws)
{
    const int t    = threadIdx.x;
    const int lane = t & 63;     // j within half
    const int wv   = t >> 6;     // wave id: owns v in [wv*16, wv*16+16)
    const int ch   = blockIdx.x & 1;
    const int b    = blockIdx.x >> 1;
    const int j    = ch * 64 + lane;

    float Mv[16];
    #pragma unroll
    for (int i = 0; i < 16; ++i) Mv[i] = Mv0[(wv * 16 + i) * 128 + j];

    __shared__ float wb[2][8][64];    // [buf][step][v]
    __shared__ float ebuf[2][8][64];  // [buf][step][j]
    __shared__ float abuf[2][8][64];
    __shared__ float part[2][4][64];  // [step parity][wave][j]

    const float4* wp = (const float4*)(w_ws + (size_t)b * 200 * 64);
    const float4* ep = (const float4*)(e_ws + (size_t)(b * 2 + ch) * 200 * 64);
    const float4* ap = (const float4*)(a_ws + (size_t)(b * 2 + ch) * 200 * 64);
    float* rp = reads_ws + (size_t)b * 200 * 128 + j;

    // staging plan per chunk (384 float4): t<128 -> w4[t] and a4[t];
    // t>=128 -> e4[t-128]
    float4 rw, ra, re;
    if (t < 128) { rw = wp[t]; ra = ap[t]; }
    else         { re = ep[t - 128]; }
    if (t < 128) { ((float4*)wb[0])[t] = rw; ((float4*)abuf[0])[t] = ra; }
    else         { ((float4*)ebuf[0])[t - 128] = re; }
    __syncthreads();

    int cb = 0;
    for (int c = 0; c < 25; ++c) {
        if (c < 24) {   // issue next-chunk loads (hidden under this chunk's compute)
            const int o = (c + 1) * 128;
            if (t < 128) { rw = wp[o + t]; ra = ap[o + t]; }
            else         { re = ep[o + t - 128]; }
        }
        #pragma unroll
        for (int st = 0; st < 8; ++st) {
            const float e_j = ebuf[cb][st][lane];
            const float a_j = abuf[cb][st][lane];
            const float* wrow = &wb[cb][st][wv * 16];
            float r0 = 0.f, r1 = 0.f, r2 = 0.f, r3 = 0.f;
            #pragma unroll
            for (int v4 = 0; v4 < 4; ++v4) {
                const float4 w4 = *(const float4*)&wrow[v4 * 4];  // broadcast
                const int v = v4 * 4;
                r0 = fmaf(w4.x, Mv[v + 0], r0);
                Mv[v + 0] = fmaf(w4.x, fmaf(-Mv[v + 0], e_j, a_j), Mv[v + 0]);
                r1 = fmaf(w4.y, Mv[v + 1], r1);
                Mv[v + 1] = fmaf(w4.y, fmaf(-Mv[v + 1], e_j, a_j), Mv[v + 1]);
                r2 = fmaf(w4.z, Mv[v + 2], r2);
                Mv[v + 2] = fmaf(w4.z, fmaf(-Mv[v + 2], e_j, a_j), Mv[v + 2]);
                r3 = fmaf(w4.w, Mv[v + 3], r3);
                Mv[v + 3] = fmaf(w4.w, fmaf(-Mv[v + 3], e_j, a_j), Mv[v + 3]);
            }
            part[st & 1][wv][lane] = (r0 + r1) + (r2 + r3);
            // fold next-chunk staging writes into the last step's barrier
            if (st == 7 && c < 24) {
                const int nb = cb ^ 1;
                if (t < 128) { ((float4*)wb[nb])[t] = rw; ((float4*)abuf[nb])[t] = ra; }
                else         { ((float4*)ebuf[nb])[t - 128] = re; }
            }
            __syncthreads();
            if (wv == 0) {
                const float r = (part[st & 1][0][lane] + part[st & 1][1][lane])
                              + (part[st & 1][2][lane] + part[st & 1][3][lane]);
                rp[(size_t)(c * 8 + st) * 128] = r;
            }
        }
        cb ^= 1;
    }
}

// ---------------------------------------------------------------------------
// Kernel C: output head. 16 rows per 256-thread block. 1600 blocks.
// ---------------------------------------------------------------------------
__global__ __launch_bounds__(256) void out_kernel(
    const int* __restrict__ qseq, const float* __restrict__ k_emb,
    const float* __restrict__ reads_ws,
    const float* __restrict__ fW, const float* __restrict__ fb,
    const float* __restrict__ pW, const float* __restrict__ pb,
    float* __restrict__ out)
{
    __shared__ float in_lds[16][256];
    __shared__ float red[16][128];
    __shared__ int qi[16];
    const int t  = threadIdx.x;
    const int R0 = blockIdx.x * 16;
    if (t < 16) qi[t] = qseq[R0 + t];
    __syncthreads();
    for (int idx = t; idx < 512; idx += 256) {
        const int r = idx >> 5, i4 = idx & 31;
        *(float4*)&in_lds[r][i4 * 4]       = *(const float4*)(reads_ws + (size_t)(R0 + r) * 128 + i4 * 4);
        *(float4*)&in_lds[r][128 + i4 * 4] = *(const float4*)(k_emb + (size_t)qi[r] * 128 + i4 * 4);
    }
    __syncthreads();
    const int j = t & 127;
    const int h = t >> 7;
    float acc[8];
    #pragma unroll
    for (int r = 0; r < 8; ++r) acc[r] = 0.f;
    for (int i0 = 0; i0 < 256; i0 += 4) {
        float fw[4];
        #pragma unroll
        for (int ii = 0; ii < 4; ++ii) fw[ii] = fW[(i0 + ii) * 128 + j];
        #pragma unroll
        for (int r = 0; r < 8; ++r) {
            const float4 v4 = *(const float4*)&in_lds[h * 8 + r][i0];
            acc[r] = fmaf(v4.x, fw[0], acc[r]);
            acc[r] = fmaf(v4.y, fw[1], acc[r]);
            acc[r] = fmaf(v4.z, fw[2], acc[r]);
            acc[r] = fmaf(v4.w, fw[3], acc[r]);
        }
    }
    const float fbj = fb[j], pwj = pW[j];
    #pragma unroll
    for (int r = 0; r < 8; ++r) {
        red[h * 8 + r][j] = tanhf(acc[r] + fbj) * pwj;
    }
    __syncthreads();
    if (t < 16) {
        float s = 0.f;
        const float4* p = (const float4*)red[t];
        #pragma unroll 8
        for (int k4 = 0; k4 < 32; ++k4) {
            const float4 x = p[k4];
            s += (x.x + x.y) + (x.z + x.w);
        }
        out[R0 + t] = sigm(s + pb[0]);
    }
}

// ---------------------------------------------------------------------------
extern "C" void kernel_launch(void* const* d_in, const int* in_sizes, int n_in,
                              void* d_out, int out_size, void* d_ws, size_t ws_size,
                              hipStream_t stream)
{
    const int*   qseq  = (const int*)d_in[0];
    const int*   cseq  = (const int*)d_in[1];
    const float* k_emb = (const float*)d_in[2];
    const float* v_emb = (const float*)d_in[3];
    const float* Mk    = (const float*)d_in[4];
    const float* Mv0   = (const float*)d_in[5];
    const float* fW    = (const float*)d_in[6];
    const float* fb    = (const float*)d_in[7];
    const float* eW    = (const float*)d_in[8];
    const float* eb    = (const float*)d_in[9];
    const float* aW    = (const float*)d_in[10];
    const float* ab    = (const float*)d_in[11];
    const float* pW    = (const float*)d_in[12];
    const float* pb    = (const float*)d_in[13];
    const int num_q = in_sizes[2] / 128;

    float* ws = (float*)d_ws;
    float* w_ws     = ws;                              // 128*200*64
    float* e_ws     = w_ws + (size_t)128 * 200 * 64;   // 128*200*128
    float* a_ws     = e_ws + (size_t)128 * 200 * 128;  // 128*200*128
    float* reads_ws = a_ws + (size_t)128 * 200 * 128;  // 128*200*128

    wea_kernel<<<1600, 256, 0, stream>>>(qseq, cseq, k_emb, v_emb, Mk,
                                         eW, eb, aW, ab, num_q,
                                         w_ws, e_ws, a_ws);
    scan_kernel<<<256, 256, 0, stream>>>(Mv0, w_ws, e_ws, a_ws, reads_ws);
    out_kernel<<<1600, 256, 0, stream>>>(qseq, k_emb, reads_ws, fW, fb, pW, pb,
                                         (float*)d_out);
}

// Round 3
// 123.334 us; speedup vs baseline: 1.8702x; 1.2940x over previous
//
#include <hip/hip_runtime.h>
#include <math.h>

// DKVMN forward: B=128, S=200, DK=128, DV=64, NUM_Q=10000
// Restructure: precompute over VOCAB (not tokens), gather in the scan.
//   prep  : transpose+convert weights to bf16 [n][k]
//   vw    : w_all = softmax(k_emb @ Mk^T)        [num_q x 64]   (fp32 VALU)
//   veakf : e_all/a_all = act(v_emb@{eW,aW}+b)   [2num_q x 128] (bf16 MFMA)
//           kf_all = k_emb @ fW[128:] + fb       [num_q x 128]  (bf16 MFMA)
//   scan  : sequential memory update, gathers w/e/a rows per token
//   out   : p = sigmoid(tanh(reads@fW[:128] + kf_all[q]) @ pW + pb)  (MFMA)

typedef float f32x4 __attribute__((ext_vector_type(4)));
typedef short bf16x8 __attribute__((ext_vector_type(8)));

__device__ __forceinline__ float sigm(float x) { return 1.0f / (1.0f + __expf(-x)); }
__device__ __forceinline__ short f2bf(float x) {
    union { float f; unsigned u; } v; v.f = x;
    return (short)((v.u + 0x7FFFu + ((v.u >> 16) & 1u)) >> 16);   // RNE
}

// ---------------------------------------------------------------------------
// prep: 4 blocks x 128 threads. dst[n*128+k] = bf16(src[k*128+n]).
// ---------------------------------------------------------------------------
__global__ __launch_bounds__(128) void prep_kernel(
    const float* __restrict__ eW, const float* __restrict__ aW,
    const float* __restrict__ fW,
    short* __restrict__ eWt, short* __restrict__ aWt,
    short* __restrict__ fWrt, short* __restrict__ fWkt)
{
    const float* src; short* dst;
    switch (blockIdx.x) {
        case 0:  src = eW;             dst = eWt;  break;
        case 1:  src = aW;             dst = aWt;  break;
        case 2:  src = fW;             dst = fWrt; break;
        default: src = fW + 128 * 128; dst = fWkt; break;
    }
    const int n = threadIdx.x;
    for (int k0 = 0; k0 < 128; k0 += 8) {
        bf16x8 v;
        #pragma unroll
        for (int kk = 0; kk < 8; ++kk) v[kk] = f2bf(src[(k0 + kk) * 128 + n]);
        *(bf16x8*)(dst + n * 128 + k0) = v;
    }
}

// ---------------------------------------------------------------------------
// vw: 16 vocab rows per 256-thread block. fp32 VALU + wave softmax.
// ---------------------------------------------------------------------------
__global__ __launch_bounds__(256) void vw_kernel(
    const float* __restrict__ k_emb, const float* __restrict__ Mk,
    int num_q, float* __restrict__ w_all)
{
    __shared__ float k_lds[16][128];
    __shared__ float mk_lds[64 * 130];
    const int t = threadIdx.x;
    const int R0 = blockIdx.x * 16;
    for (int idx = t; idx < 2048; idx += 256) {
        const int dv = idx >> 5, i4 = idx & 31;
        const float4 m4 = *(const float4*)(Mk + dv * 128 + i4 * 4);
        float* d = &mk_lds[dv * 130 + i4 * 4];
        d[0] = m4.x; d[1] = m4.y; d[2] = m4.z; d[3] = m4.w;
    }
    for (int idx = t; idx < 512; idx += 256) {
        const int r = idx >> 5, i4 = idx & 31;
        int gr = R0 + r; if (gr > num_q - 1) gr = num_q - 1;
        *(float4*)&k_lds[r][i4 * 4] = *(const float4*)(k_emb + (size_t)gr * 128 + i4 * 4);
    }
    __syncthreads();
    const int dv = t & 63;
    const int wvv = t >> 6;
    const float* mkrow = &mk_lds[dv * 130];
    #pragma unroll
    for (int rr = 0; rr < 4; ++rr) {
        const int r = wvv * 4 + rr;
        float acc = 0.f;
        #pragma unroll 8
        for (int i = 0; i < 128; i += 2) {
            const float2 m2 = *(const float2*)&mkrow[i];
            const float2 k2 = *(const float2*)&k_lds[r][i];
            acc = fmaf(k2.x, m2.x, acc);
            acc = fmaf(k2.y, m2.y, acc);
        }
        float m = acc;
        #pragma unroll
        for (int o = 32; o; o >>= 1) m = fmaxf(m, __shfl_xor(m, o));
        const float ex = __expf(acc - m);
        float sm = ex;
        #pragma unroll
        for (int o = 32; o; o >>= 1) sm += __shfl_xor(sm, o);
        const int R = R0 + r;
        if (R < num_q) w_all[(size_t)R * 64 + dv] = ex / sm;
    }
}

// ---------------------------------------------------------------------------
// veakf: 64 vocab rows per block, 4 waves, bf16 MFMA 16x16x32.
// blocks [0,nbe): e/a over v_emb.  blocks [nbe,..): kf over k_emb.
// A staged in LDS with XOR-16B swizzle; B fragments read from global (L2-hot).
// ---------------------------------------------------------------------------
__global__ __launch_bounds__(256) void veakf_kernel(
    const float* __restrict__ v_emb, const float* __restrict__ k_emb,
    const short* __restrict__ eWt, const short* __restrict__ aWt,
    const short* __restrict__ fWkt,
    const float* __restrict__ eb, const float* __restrict__ ab,
    const float* __restrict__ fb,
    int num_q, int nbe,
    float* __restrict__ e_all, float* __restrict__ a_all,
    float* __restrict__ kf_all)
{
    __shared__ __align__(16) short Ash[64 * 128];
    const int t = threadIdx.x;
    const bool ea = ((int)blockIdx.x < nbe);
    const int nrows = ea ? 2 * num_q : num_q;
    const int R0 = (ea ? blockIdx.x : blockIdx.x - nbe) * 64;
    const float* Asrc = ea ? v_emb : k_emb;

    #pragma unroll
    for (int i = 0; i < 4; ++i) {
        const int c = t + 256 * i;
        const int row = c >> 4, ch = c & 15;
        int gr = R0 + row; if (gr > nrows - 1) gr = nrows - 1;
        const float4 f0 = *(const float4*)(Asrc + (size_t)gr * 128 + ch * 8);
        const float4 f1 = *(const float4*)(Asrc + (size_t)gr * 128 + ch * 8 + 4);
        bf16x8 v;
        v[0] = f2bf(f0.x); v[1] = f2bf(f0.y); v[2] = f2bf(f0.z); v[3] = f2bf(f0.w);
        v[4] = f2bf(f1.x); v[5] = f2bf(f1.y); v[6] = f2bf(f1.z); v[7] = f2bf(f1.w);
        *(bf16x8*)&Ash[row * 128 + ((ch ^ (row & 7)) * 8)] = v;
    }
    __syncthreads();

    const int wv = t >> 6;
    const int lr = t & 15;
    const int lk = (t & 63) >> 4;
    const int arow = wv * 16 + lr;

    f32x4 acc0[8], acc1[8];
    #pragma unroll
    for (int ct = 0; ct < 8; ++ct) { acc0[ct] = (f32x4)0.f; acc1[ct] = (f32x4)0.f; }

    #pragma unroll
    for (int ks = 0; ks < 4; ++ks) {
        const int chunk = ks * 4 + lk;
        const bf16x8 af = *(const bf16x8*)&Ash[arow * 128 + ((chunk ^ (arow & 7)) * 8)];
        const int kb = ks * 32 + lk * 8;
        if (ea) {
            #pragma unroll
            for (int ct = 0; ct < 8; ++ct) {
                const int n = ct * 16 + lr;
                const bf16x8 b0 = *(const bf16x8*)(eWt + n * 128 + kb);
                const bf16x8 b1 = *(const bf16x8*)(aWt + n * 128 + kb);
                acc0[ct] = __builtin_amdgcn_mfma_f32_16x16x32_bf16(af, b0, acc0[ct], 0, 0, 0);
                acc1[ct] = __builtin_amdgcn_mfma_f32_16x16x32_bf16(af, b1, acc1[ct], 0, 0, 0);
            }
        } else {
            #pragma unroll
            for (int ct = 0; ct < 8; ++ct) {
                const int n = ct * 16 + lr;
                const bf16x8 b0 = *(const bf16x8*)(fWkt + n * 128 + kb);
                acc0[ct] = __builtin_amdgcn_mfma_f32_16x16x32_bf16(af, b0, acc0[ct], 0, 0, 0);
            }
        }
    }

    if (ea) {
        #pragma unroll
        for (int ct = 0; ct < 8; ++ct) {
            const int col = ct * 16 + lr;
            const float ebv = eb[col], abv = ab[col];
            #pragma unroll
            for (int r = 0; r < 4; ++r) {
                const int row = R0 + wv * 16 + lk * 4 + r;
                if (row < nrows) {
                    e_all[(size_t)row * 128 + col] = sigm(acc0[ct][r] + ebv);
                    a_all[(size_t)row * 128 + col] = tanhf(acc1[ct][r] + abv);
                }
            }
        }
    } else {
        #pragma unroll
        for (int ct = 0; ct < 8; ++ct) {
            const int col = ct * 16 + lr;
            const float fbv = fb[col];
            #pragma unroll
            for (int r = 0; r < 4; ++r) {
                const int row = R0 + wv * 16 + lk * 4 + r;
                if (row < nrows)
                    kf_all[(size_t)row * 128 + col] = acc0[ct][r] + fbv;
            }
        }
    }
}

// ---------------------------------------------------------------------------
// scan: block = (batch, column-half), 4 waves split the 64 v-slots.
// Gathers w/e/a rows from vocab tables (L2/L3), one chunk (8 steps) ahead.
// Writes reads as bf16 (feeds out_kernel's MFMA A operand).
// ---------------------------------------------------------------------------
__global__ __launch_bounds__(256) void scan_kernel(
    const float* __restrict__ Mv0,
    const int* __restrict__ qseq, const int* __restrict__ cseq,
    const float* __restrict__ w_all, const float* __restrict__ e_all,
    const float* __restrict__ a_all, int num_q,
    unsigned short* __restrict__ reads_bf)
{
    const int t    = threadIdx.x;
    const int lane = t & 63;
    const int wv   = t >> 6;
    const int ch   = blockIdx.x & 1;
    const int b    = blockIdx.x >> 1;
    const int j    = ch * 64 + lane;

    float Mv[16];
    #pragma unroll
    for (int i = 0; i < 16; ++i) Mv[i] = Mv0[(wv * 16 + i) * 128 + j];

    __shared__ float wb[2][8][64];
    __shared__ float ebuf[2][8][64];
    __shared__ float abuf[2][8][64];
    __shared__ float part[2][4][64];
    __shared__ int sq[200], sx[200];   // pre-scaled float4 row offsets

    if (t < 200) {
        const int q = qseq[b * 200 + t];
        const int c = cseq[b * 200 + t];
        sq[t] = q * 16;
        sx[t] = (q + num_q * c) * 32 + ch * 16;
    }
    __syncthreads();

    const float4* w4 = (const float4*)w_all;
    const float4* e4 = (const float4*)e_all;
    const float4* a4 = (const float4*)a_all;
    unsigned short* rp = reads_bf + (size_t)b * 200 * 128 + j;

    // chunk 0 gather -> buf 0
    float4 rw, ra, re;
    if (t < 128) {
        const int st = t >> 4, i = t & 15;
        rw = w4[sq[st] + i];
        ra = a4[sx[st] + i];
        ((float4*)wb[0])[t] = rw; ((float4*)abuf[0])[t] = ra;
    } else {
        const int u = t - 128; const int st = u >> 4, i = u & 15;
        re = e4[sx[st] + i];
        ((float4*)ebuf[0])[u] = re;
    }
    __syncthreads();

    int cb = 0;
    for (int c = 0; c < 25; ++c) {
        if (c < 24) {   // issue next-chunk gathers (hidden under this chunk)
            const int s0 = (c + 1) * 8;
            if (t < 128) {
                const int st = s0 + (t >> 4), i = t & 15;
                rw = w4[sq[st] + i];
                ra = a4[sx[st] + i];
            } else {
                const int u = t - 128; const int st = s0 + (u >> 4), i = u & 15;
                re = e4[sx[st] + i];
            }
        }
        #pragma unroll
        for (int st = 0; st < 8; ++st) {
            const float e_j = ebuf[cb][st][lane];
            const float a_j = abuf[cb][st][lane];
            const float* wrow = &wb[cb][st][wv * 16];
            float r0 = 0.f, r1 = 0.f, r2 = 0.f, r3 = 0.f;
            #pragma unroll
            for (int v4i = 0; v4i < 4; ++v4i) {
                const float4 w4v = *(const float4*)&wrow[v4i * 4];  // broadcast
                const int v = v4i * 4;
                r0 = fmaf(w4v.x, Mv[v + 0], r0);
                Mv[v + 0] = fmaf(w4v.x, fmaf(-Mv[v + 0], e_j, a_j), Mv[v + 0]);
                r1 = fmaf(w4v.y, Mv[v + 1], r1);
                Mv[v + 1] = fmaf(w4v.y, fmaf(-Mv[v + 1], e_j, a_j), Mv[v + 1]);
                r2 = fmaf(w4v.z, Mv[v + 2], r2);
                Mv[v + 2] = fmaf(w4v.z, fmaf(-Mv[v + 2], e_j, a_j), Mv[v + 2]);
                r3 = fmaf(w4v.w, Mv[v + 3], r3);
                Mv[v + 3] = fmaf(w4v.w, fmaf(-Mv[v + 3], e_j, a_j), Mv[v + 3]);
            }
            part[st & 1][wv][lane] = (r0 + r1) + (r2 + r3);
            if (st == 7 && c < 24) {   // fold staging writes into last barrier
                const int nb = cb ^ 1;
                if (t < 128) { ((float4*)wb[nb])[t] = rw; ((float4*)abuf[nb])[t] = ra; }
                else         { ((float4*)ebuf[nb])[t - 128] = re; }
            }
            __syncthreads();
            if (wv == 0) {
                const float r = (part[st & 1][0][lane] + part[st & 1][1][lane])
                              + (part[st & 1][2][lane] + part[st & 1][3][lane]);
                rp[(size_t)(c * 8 + st) * 128] = (unsigned short)f2bf(r);
            }
        }
        cb ^= 1;
    }
}

// ---------------------------------------------------------------------------
// out: 64 tokens per block, bf16 MFMA. acc init = kf_all[q] (+fb already in).
// Epilogue: tanh, dot with pW, 16-lane shuffle reduce, sigmoid.
// ---------------------------------------------------------------------------
__global__ __launch_bounds__(256) void out_kernel(
    const int* __restrict__ qseq,
    const unsigned short* __restrict__ reads_bf,
    const short* __restrict__ fWrt, const float* __restrict__ kf_all,
    const float* __restrict__ pW, const float* __restrict__ pb,
    int ntok, float* __restrict__ out)
{
    __shared__ __align__(16) short Ash[64 * 128];
    __shared__ int qi[64];
    const int t = threadIdx.x;
    const int R0 = blockIdx.x * 64;
    if (t < 64) { int r = R0 + t; qi[t] = qseq[r < ntok ? r : ntok - 1]; }
    #pragma unroll
    for (int i = 0; i < 4; ++i) {
        const int c = t + 256 * i;
        const int row = c >> 4, ch = c & 15;
        int gr = R0 + row; if (gr > ntok - 1) gr = ntok - 1;
        const bf16x8 v = *(const bf16x8*)(reads_bf + (size_t)gr * 128 + ch * 8);
        *(bf16x8*)&Ash[row * 128 + ((ch ^ (row & 7)) * 8)] = v;
    }
    __syncthreads();

    const int wv = t >> 6;
    const int lr = t & 15;
    const int lk = (t & 63) >> 4;
    const int arow = wv * 16 + lr;

    f32x4 acc[8];
    #pragma unroll
    for (int ct = 0; ct < 8; ++ct) {
        const int col = ct * 16 + lr;
        #pragma unroll
        for (int r = 0; r < 4; ++r) {
            const int q = qi[wv * 16 + lk * 4 + r];
            acc[ct][r] = kf_all[(size_t)q * 128 + col];
        }
    }
    #pragma unroll
    for (int ks = 0; ks < 4; ++ks) {
        const int chunk = ks * 4 + lk;
        const bf16x8 af = *(const bf16x8*)&Ash[arow * 128 + ((chunk ^ (arow & 7)) * 8)];
        const int kb = ks * 32 + lk * 8;
        #pragma unroll
        for (int ct = 0; ct < 8; ++ct) {
            const int n = ct * 16 + lr;
            const bf16x8 bfr = *(const bf16x8*)(fWrt + n * 128 + kb);
            acc[ct] = __builtin_amdgcn_mfma_f32_16x16x32_bf16(af, bfr, acc[ct], 0, 0, 0);
        }
    }
    const float pb0 = pb[0];
    float s0 = 0.f, s1 = 0.f, s2 = 0.f, s3 = 0.f;
    #pragma unroll
    for (int ct = 0; ct < 8; ++ct) {
        const float pw = pW[ct * 16 + lr];
        s0 = fmaf(tanhf(acc[ct][0]), pw, s0);
        s1 = fmaf(tanhf(acc[ct][1]), pw, s1);
        s2 = fmaf(tanhf(acc[ct][2]), pw, s2);
        s3 = fmaf(tanhf(acc[ct][3]), pw, s3);
    }
    #pragma unroll
    for (int off = 1; off < 16; off <<= 1) {
        s0 += __shfl_xor(s0, off);
        s1 += __shfl_xor(s1, off);
        s2 += __shfl_xor(s2, off);
        s3 += __shfl_xor(s3, off);
    }
    if (lr == 0) {
        const int row = R0 + wv * 16 + lk * 4;
        if (row + 0 < ntok) out[row + 0] = sigm(s0 + pb0);
        if (row + 1 < ntok) out[row + 1] = sigm(s1 + pb0);
        if (row + 2 < ntok) out[row + 2] = sigm(s2 + pb0);
        if (row + 3 < ntok) out[row + 3] = sigm(s3 + pb0);
    }
}

// ---------------------------------------------------------------------------
extern "C" void kernel_launch(void* const* d_in, const int* in_sizes, int n_in,
                              void* d_out, int out_size, void* d_ws, size_t ws_size,
                              hipStream_t stream)
{
    const int*   qseq  = (const int*)d_in[0];
    const int*   cseq  = (const int*)d_in[1];
    const float* k_emb = (const float*)d_in[2];
    const float* v_emb = (const float*)d_in[3];
    const float* Mk    = (const float*)d_in[4];
    const float* Mv0   = (const float*)d_in[5];
    const float* fW    = (const float*)d_in[6];
    const float* fb    = (const float*)d_in[7];
    const float* eW    = (const float*)d_in[8];
    const float* eb    = (const float*)d_in[9];
    const float* aW    = (const float*)d_in[10];
    const float* ab    = (const float*)d_in[11];
    const float* pW    = (const float*)d_in[12];
    const float* pb    = (const float*)d_in[13];

    const int num_q = in_sizes[2] / 128;   // 10000
    const int ntok  = in_sizes[0];         // B*S = 25600
    const int Bb    = ntok / 200;          // 128
    const int NV    = 2 * num_q;

    float* ws = (float*)d_ws;
    float* w_all  = ws;                                  // num_q*64
    float* e_all  = w_all  + (size_t)num_q * 64;         // NV*128
    float* a_all  = e_all  + (size_t)NV * 128;           // NV*128
    float* kf_all = a_all  + (size_t)NV * 128;           // num_q*128
    short* eWt    = (short*)(kf_all + (size_t)num_q * 128);
    short* aWt    = eWt  + 128 * 128;
    short* fWrt   = aWt  + 128 * 128;
    short* fWkt   = fWrt + 128 * 128;
    unsigned short* reads_bf = (unsigned short*)(fWkt + 128 * 128);  // ntok*128 bf16
    // total ~34.9 MB of d_ws

    prep_kernel<<<4, 128, 0, stream>>>(eW, aW, fW, eWt, aWt, fWrt, fWkt);
    vw_kernel<<<(num_q + 15) / 16, 256, 0, stream>>>(k_emb, Mk, num_q, w_all);
    const int nbe = (NV + 63) / 64, nbk = (num_q + 63) / 64;
    veakf_kernel<<<nbe + nbk, 256, 0, stream>>>(v_emb, k_emb, eWt, aWt, fWkt,
                                                eb, ab, fb, num_q, nbe,
                                                e_all, a_all, kf_all);
    scan_kernel<<<Bb * 2, 256, 0, stream>>>(Mv0, qseq, cseq, w_all, e_all, a_all,
                                            num_q, reads_bf);
    out_kernel<<<(ntok + 63) / 64, 256, 0, stream>>>(qseq, reads_bf, fWrt, kf_all,
                                                     pW, pb, ntok, (float*)d_out);
}

// Round 4
// 77.564 us; speedup vs baseline: 2.9738x; 1.5901x over previous
//
#include <hip/hip_runtime.h>
#include <math.h>

// DKVMN forward: B=128, S=200, DK=128, DV=64, NUM_Q=10000
//   prep  : convert weights to bf16 [n][k] (+ Mk straight bf16)
//   veakf : e_all/a_all = act(v_emb@{eW,aW}+b)   [2num_q x 128] (bf16 MFMA)
//           kf_all = k_emb @ fW[128:] + fb,  w_all = softmax(k_emb@Mk^T)
//   scan  : sequential memory update; barrier-free steps, per-chunk reduce
//   out   : p = sigmoid(tanh(reads@fW[:128] + kf_all[q]) @ pW + pb)  (MFMA)

typedef float f32x4 __attribute__((ext_vector_type(4)));
typedef short bf16x8 __attribute__((ext_vector_type(8)));

__device__ __forceinline__ float sigm(float x) { return 1.0f / (1.0f + __expf(-x)); }
__device__ __forceinline__ short f2bf(float x) {
    union { float f; unsigned u; } v; v.f = x;
    return (short)((v.u + 0x7FFFu + ((v.u >> 16) & 1u)) >> 16);   // RNE
}

// ---------------------------------------------------------------------------
// prep: 5 blocks x 128 threads.
// blocks 0-3: dst[n*128+k] = bf16(src[k*128+n]) (transpose). block 4: Mk copy.
// ---------------------------------------------------------------------------
__global__ __launch_bounds__(128) void prep_kernel(
    const float* __restrict__ eW, const float* __restrict__ aW,
    const float* __restrict__ fW, const float* __restrict__ Mk,
    short* __restrict__ eWt, short* __restrict__ aWt,
    short* __restrict__ fWrt, short* __restrict__ fWkt,
    short* __restrict__ Mkb)
{
    const int t = threadIdx.x;
    if (blockIdx.x == 4) {   // Mk [64][128] -> bf16, no transpose
        for (int idx = t; idx < 1024; idx += 128) {
            const int row = idx >> 4, c8 = idx & 15;
            const float4 f0 = *(const float4*)(Mk + row * 128 + c8 * 8);
            const float4 f1 = *(const float4*)(Mk + row * 128 + c8 * 8 + 4);
            bf16x8 v;
            v[0] = f2bf(f0.x); v[1] = f2bf(f0.y); v[2] = f2bf(f0.z); v[3] = f2bf(f0.w);
            v[4] = f2bf(f1.x); v[5] = f2bf(f1.y); v[6] = f2bf(f1.z); v[7] = f2bf(f1.w);
            *(bf16x8*)(Mkb + row * 128 + c8 * 8) = v;
        }
        return;
    }
    const float* src; short* dst;
    switch (blockIdx.x) {
        case 0:  src = eW;             dst = eWt;  break;
        case 1:  src = aW;             dst = aWt;  break;
        case 2:  src = fW;             dst = fWrt; break;
        default: src = fW + 128 * 128; dst = fWkt; break;
    }
    const int n = t;
    for (int k0 = 0; k0 < 128; k0 += 8) {
        bf16x8 v;
        #pragma unroll
        for (int kk = 0; kk < 8; ++kk) v[kk] = f2bf(src[(k0 + kk) * 128 + n]);
        *(bf16x8*)(dst + n * 128 + k0) = v;
    }
}

// ---------------------------------------------------------------------------
// veakf: 64 vocab rows per block, 4 waves, bf16 MFMA 16x16x32.
// blocks [0,nbe): e/a over v_emb.  blocks [nbe,..): kf + w over k_emb.
// ---------------------------------------------------------------------------
__global__ __launch_bounds__(256) void veakf_kernel(
    const float* __restrict__ v_emb, const float* __restrict__ k_emb,
    const short* __restrict__ eWt, const short* __restrict__ aWt,
    const short* __restrict__ fWkt, const short* __restrict__ Mkb,
    const float* __restrict__ eb, const float* __restrict__ ab,
    const float* __restrict__ fb,
    int num_q, int nbe,
    float* __restrict__ e_all, float* __restrict__ a_all,
    float* __restrict__ kf_all, float* __restrict__ w_all)
{
    __shared__ __align__(16) short Ash[64 * 128];
    const int t = threadIdx.x;
    const bool ea = ((int)blockIdx.x < nbe);
    const int nrows = ea ? 2 * num_q : num_q;
    const int R0 = (ea ? blockIdx.x : blockIdx.x - nbe) * 64;
    const float* Asrc = ea ? v_emb : k_emb;

    #pragma unroll
    for (int i = 0; i < 4; ++i) {
        const int c = t + 256 * i;
        const int row = c >> 4, ch = c & 15;
        int gr = R0 + row; if (gr > nrows - 1) gr = nrows - 1;
        const float4 f0 = *(const float4*)(Asrc + (size_t)gr * 128 + ch * 8);
        const float4 f1 = *(const float4*)(Asrc + (size_t)gr * 128 + ch * 8 + 4);
        bf16x8 v;
        v[0] = f2bf(f0.x); v[1] = f2bf(f0.y); v[2] = f2bf(f0.z); v[3] = f2bf(f0.w);
        v[4] = f2bf(f1.x); v[5] = f2bf(f1.y); v[6] = f2bf(f1.z); v[7] = f2bf(f1.w);
        *(bf16x8*)&Ash[row * 128 + ((ch ^ (row & 7)) * 8)] = v;
    }
    __syncthreads();

    const int wv = t >> 6;
    const int lr = t & 15;
    const int lk = (t & 63) >> 4;
    const int arow = wv * 16 + lr;

    if (ea) {
        f32x4 acc0[8], acc1[8];
        #pragma unroll
        for (int ct = 0; ct < 8; ++ct) { acc0[ct] = (f32x4)0.f; acc1[ct] = (f32x4)0.f; }
        #pragma unroll
        for (int ks = 0; ks < 4; ++ks) {
            const int chunk = ks * 4 + lk;
            const bf16x8 af = *(const bf16x8*)&Ash[arow * 128 + ((chunk ^ (arow & 7)) * 8)];
            const int kb = ks * 32 + lk * 8;
            #pragma unroll
            for (int ct = 0; ct < 8; ++ct) {
                const int n = ct * 16 + lr;
                const bf16x8 b0 = *(const bf16x8*)(eWt + n * 128 + kb);
                const bf16x8 b1 = *(const bf16x8*)(aWt + n * 128 + kb);
                acc0[ct] = __builtin_amdgcn_mfma_f32_16x16x32_bf16(af, b0, acc0[ct], 0, 0, 0);
                acc1[ct] = __builtin_amdgcn_mfma_f32_16x16x32_bf16(af, b1, acc1[ct], 0, 0, 0);
            }
        }
        #pragma unroll
        for (int ct = 0; ct < 8; ++ct) {
            const int col = ct * 16 + lr;
            const float ebv = eb[col], abv = ab[col];
            #pragma unroll
            for (int r = 0; r < 4; ++r) {
                const int row = R0 + wv * 16 + lk * 4 + r;
                if (row < nrows) {
                    e_all[(size_t)row * 128 + col] = sigm(acc0[ct][r] + ebv);
                    a_all[(size_t)row * 128 + col] = tanhf(acc1[ct][r] + abv);
                }
            }
        }
    } else {
        f32x4 acc0[8], accw[4];
        #pragma unroll
        for (int ct = 0; ct < 8; ++ct) acc0[ct] = (f32x4)0.f;
        #pragma unroll
        for (int ct = 0; ct < 4; ++ct) accw[ct] = (f32x4)0.f;
        #pragma unroll
        for (int ks = 0; ks < 4; ++ks) {
            const int chunk = ks * 4 + lk;
            const bf16x8 af = *(const bf16x8*)&Ash[arow * 128 + ((chunk ^ (arow & 7)) * 8)];
            const int kb = ks * 32 + lk * 8;
            #pragma unroll
            for (int ct = 0; ct < 8; ++ct) {
                const int n = ct * 16 + lr;
                const bf16x8 b0 = *(const bf16x8*)(fWkt + n * 128 + kb);
                acc0[ct] = __builtin_amdgcn_mfma_f32_16x16x32_bf16(af, b0, acc0[ct], 0, 0, 0);
            }
            #pragma unroll
            for (int ct = 0; ct < 4; ++ct) {
                const int n = ct * 16 + lr;
                const bf16x8 bm = *(const bf16x8*)(Mkb + n * 128 + kb);
                accw[ct] = __builtin_amdgcn_mfma_f32_16x16x32_bf16(af, bm, accw[ct], 0, 0, 0);
            }
        }
        #pragma unroll
        for (int ct = 0; ct < 8; ++ct) {
            const int col = ct * 16 + lr;
            const float fbv = fb[col];
            #pragma unroll
            for (int r = 0; r < 4; ++r) {
                const int row = R0 + wv * 16 + lk * 4 + r;
                if (row < nrows)
                    kf_all[(size_t)row * 128 + col] = acc0[ct][r] + fbv;
            }
        }
        // softmax over 64 memory slots (4 ct regs x 16 lr lanes)
        #pragma unroll
        for (int r = 0; r < 4; ++r) {
            const float x0 = accw[0][r], x1 = accw[1][r];
            const float x2 = accw[2][r], x3 = accw[3][r];
            float m = fmaxf(fmaxf(x0, x1), fmaxf(x2, x3));
            #pragma unroll
            for (int mk = 1; mk < 16; mk <<= 1) m = fmaxf(m, __shfl_xor(m, mk));
            const float e0 = __expf(x0 - m), e1 = __expf(x1 - m);
            const float e2 = __expf(x2 - m), e3 = __expf(x3 - m);
            float s = (e0 + e1) + (e2 + e3);
            #pragma unroll
            for (int mk = 1; mk < 16; mk <<= 1) s += __shfl_xor(s, mk);
            const float inv = 1.0f / s;
            const int row = R0 + wv * 16 + lk * 4 + r;
            if (row < nrows) {
                float* wr = w_all + (size_t)row * 64 + lr;
                wr[0]  = e0 * inv; wr[16] = e1 * inv;
                wr[32] = e2 * inv; wr[48] = e3 * inv;
            }
        }
    }
}

// ---------------------------------------------------------------------------
// scan: block = (batch, j-quarter of 32), 256 threads = 8 v-groups x 32 j.
// Recurrence is independent per (v,j): NO per-step barrier. Partial reads go
// to double-buffered LDS; one barrier + reduce per 8-step chunk. Gathers
// w/e/a rows from vocab tables one chunk ahead. 512 blocks -> 8 waves/CU.
// ---------------------------------------------------------------------------
__global__ __launch_bounds__(256) void scan_kernel(
    const float* __restrict__ Mv0,
    const int* __restrict__ qseq, const int* __restrict__ cseq,
    const float* __restrict__ w_all, const float* __restrict__ e_all,
    const float* __restrict__ a_all, int num_q,
    unsigned short* __restrict__ reads_bf)
{
    const int t  = threadIdx.x;
    const int j  = t & 31;          // column within quarter
    const int vg = t >> 5;          // v-group: owns slots [vg*8, vg*8+8)
    const int cq = blockIdx.x & 3;
    const int b  = blockIdx.x >> 2;
    const int jg = cq * 32 + j;

    float Mv[8];
    #pragma unroll
    for (int i = 0; i < 8; ++i) Mv[i] = Mv0[(vg * 8 + i) * 128 + jg];

    __shared__ float wb[2][8][64];
    __shared__ float ebuf[2][8][32];
    __shared__ float abuf[2][8][32];
    __shared__ float part[2][8][8][32];   // [buf][step][vg][j]
    __shared__ int sq[200], sx[200];

    if (t < 200) {
        const int q = qseq[b * 200 + t];
        const int c = cseq[b * 200 + t];
        sq[t] = q * 16;                       // float4 row offset in w_all
        sx[t] = (q + num_q * c) * 32 + cq * 8; // float4 offset in e/a quarter
    }
    __syncthreads();

    const float4* w4 = (const float4*)w_all;
    const float4* e4 = (const float4*)e_all;
    const float4* a4 = (const float4*)a_all;
    unsigned short* rp = reads_bf + (size_t)b * 200 * 128 + jg;

    // chunk 0 gather -> buf 0 (1 float4 per thread)
    float4 rg;
    if (t < 128)      { rg = w4[sq[t >> 4] + (t & 15)];               ((float4*)wb[0])[t] = rg; }
    else if (t < 192) { const int u = t - 128; rg = e4[sx[u >> 3] + (u & 7)]; ((float4*)ebuf[0])[u] = rg; }
    else              { const int u = t - 192; rg = a4[sx[u >> 3] + (u & 7)]; ((float4*)abuf[0])[u] = rg; }
    __syncthreads();

    int cb = 0, pbuf = 0;
    for (int c = 0; c < 25; ++c) {
        if (c < 24) {   // issue next-chunk gathers (complete under this chunk)
            const int s0 = (c + 1) * 8;
            if (t < 128)      rg = w4[sq[s0 + (t >> 4)] + (t & 15)];
            else if (t < 192) { const int u = t - 128; rg = e4[sx[s0 + (u >> 3)] + (u & 7)]; }
            else              { const int u = t - 192; rg = a4[sx[s0 + (u >> 3)] + (u & 7)]; }
        }
        #pragma unroll
        for (int st = 0; st < 8; ++st) {
            const float e_j = ebuf[cb][st][j];
            const float a_j = abuf[cb][st][j];
            const float* wrow = &wb[cb][st][vg * 8];
            float r0 = 0.f, r1 = 0.f, r2 = 0.f, r3 = 0.f;
            #pragma unroll
            for (int v4i = 0; v4i < 2; ++v4i) {
                const float4 w4v = *(const float4*)&wrow[v4i * 4];  // broadcast
                const int v = v4i * 4;
                r0 = fmaf(w4v.x, Mv[v + 0], r0);
                Mv[v + 0] = fmaf(w4v.x, fmaf(-Mv[v + 0], e_j, a_j), Mv[v + 0]);
                r1 = fmaf(w4v.y, Mv[v + 1], r1);
                Mv[v + 1] = fmaf(w4v.y, fmaf(-Mv[v + 1], e_j, a_j), Mv[v + 1]);
                r2 = fmaf(w4v.z, Mv[v + 2], r2);
                Mv[v + 2] = fmaf(w4v.z, fmaf(-Mv[v + 2], e_j, a_j), Mv[v + 2]);
                r3 = fmaf(w4v.w, Mv[v + 3], r3);
                Mv[v + 3] = fmaf(w4v.w, fmaf(-Mv[v + 3], e_j, a_j), Mv[v + 3]);
            }
            part[pbuf][st][vg][j] = (r0 + r1) + (r2 + r3);
        }
        if (c < 24) {   // stage next chunk (regs -> other buffer)
            if (t < 128)      ((float4*)wb[cb ^ 1])[t] = rg;
            else if (t < 192) ((float4*)ebuf[cb ^ 1])[t - 128] = rg;
            else              ((float4*)abuf[cb ^ 1])[t - 192] = rg;
        }
        __syncthreads();
        // reduce: one (step, j) per thread, sum 8 v-group partials
        {
            const int st = t >> 5, jr = t & 31;
            const float* pp = &part[pbuf][st][0][jr];
            float r = 0.f;
            #pragma unroll
            for (int g = 0; g < 8; ++g) r += pp[g * 32];
            reads_bf[(size_t)b * 200 * 128 + (size_t)(c * 8 + st) * 128 + cq * 32 + jr]
                = (unsigned short)f2bf(r);
        }
        cb ^= 1; pbuf ^= 1;
    }
    (void)rp;
}

// ---------------------------------------------------------------------------
// out: 64 tokens per block, bf16 MFMA. acc init = kf_all[q] (+fb already in).
// ---------------------------------------------------------------------------
__global__ __launch_bounds__(256) void out_kernel(
    const int* __restrict__ qseq,
    const unsigned short* __restrict__ reads_bf,
    const short* __restrict__ fWrt, const float* __restrict__ kf_all,
    const float* __restrict__ pW, const float* __restrict__ pb,
    int ntok, float* __restrict__ out)
{
    __shared__ __align__(16) short Ash[64 * 128];
    __shared__ int qi[64];
    const int t = threadIdx.x;
    const int R0 = blockIdx.x * 64;
    if (t < 64) { int r = R0 + t; qi[t] = qseq[r < ntok ? r : ntok - 1]; }
    #pragma unroll
    for (int i = 0; i < 4; ++i) {
        const int c = t + 256 * i;
        const int row = c >> 4, ch = c & 15;
        int gr = R0 + row; if (gr > ntok - 1) gr = ntok - 1;
        const bf16x8 v = *(const bf16x8*)(reads_bf + (size_t)gr * 128 + ch * 8);
        *(bf16x8*)&Ash[row * 128 + ((ch ^ (row & 7)) * 8)] = v;
    }
    __syncthreads();

    const int wv = t >> 6;
    const int lr = t & 15;
    const int lk = (t & 63) >> 4;
    const int arow = wv * 16 + lr;

    f32x4 acc[8];
    #pragma unroll
    for (int ct = 0; ct < 8; ++ct) {
        const int col = ct * 16 + lr;
        #pragma unroll
        for (int r = 0; r < 4; ++r) {
            const int q = qi[wv * 16 + lk * 4 + r];
            acc[ct][r] = kf_all[(size_t)q * 128 + col];
        }
    }
    #pragma unroll
    for (int ks = 0; ks < 4; ++ks) {
        const int chunk = ks * 4 + lk;
        const bf16x8 af = *(const bf16x8*)&Ash[arow * 128 + ((chunk ^ (arow & 7)) * 8)];
        const int kb = ks * 32 + lk * 8;
        #pragma unroll
        for (int ct = 0; ct < 8; ++ct) {
            const int n = ct * 16 + lr;
            const bf16x8 bfr = *(const bf16x8*)(fWrt + n * 128 + kb);
            acc[ct] = __builtin_amdgcn_mfma_f32_16x16x32_bf16(af, bfr, acc[ct], 0, 0, 0);
        }
    }
    const float pb0 = pb[0];
    float s0 = 0.f, s1 = 0.f, s2 = 0.f, s3 = 0.f;
    #pragma unroll
    for (int ct = 0; ct < 8; ++ct) {
        const float pw = pW[ct * 16 + lr];
        s0 = fmaf(tanhf(acc[ct][0]), pw, s0);
        s1 = fmaf(tanhf(acc[ct][1]), pw, s1);
        s2 = fmaf(tanhf(acc[ct][2]), pw, s2);
        s3 = fmaf(tanhf(acc[ct][3]), pw, s3);
    }
    #pragma unroll
    for (int off = 1; off < 16; off <<= 1) {
        s0 += __shfl_xor(s0, off);
        s1 += __shfl_xor(s1, off);
        s2 += __shfl_xor(s2, off);
        s3 += __shfl_xor(s3, off);
    }
    if (lr == 0) {
        const int row = R0 + wv * 16 + lk * 4;
        if (row + 0 < ntok) out[row + 0] = sigm(s0 + pb0);
        if (row + 1 < ntok) out[row + 1] = sigm(s1 + pb0);
        if (row + 2 < ntok) out[row + 2] = sigm(s2 + pb0);
        if (row + 3 < ntok) out[row + 3] = sigm(s3 + pb0);
    }
}

// ---------------------------------------------------------------------------
extern "C" void kernel_launch(void* const* d_in, const int* in_sizes, int n_in,
                              void* d_out, int out_size, void* d_ws, size_t ws_size,
                              hipStream_t stream)
{
    const int*   qseq  = (const int*)d_in[0];
    const int*   cseq  = (const int*)d_in[1];
    const float* k_emb = (const float*)d_in[2];
    const float* v_emb = (const float*)d_in[3];
    const float* Mk    = (const float*)d_in[4];
    const float* Mv0   = (const float*)d_in[5];
    const float* fW    = (const float*)d_in[6];
    const float* fb    = (const float*)d_in[7];
    const float* eW    = (const float*)d_in[8];
    const float* eb    = (const float*)d_in[9];
    const float* aW    = (const float*)d_in[10];
    const float* ab    = (const float*)d_in[11];
    const float* pW    = (const float*)d_in[12];
    const float* pb    = (const float*)d_in[13];

    const int num_q = in_sizes[2] / 128;   // 10000
    const int ntok  = in_sizes[0];         // B*S = 25600
    const int Bb    = ntok / 200;          // 128
    const int NV    = 2 * num_q;

    float* ws = (float*)d_ws;
    float* w_all  = ws;                                  // num_q*64
    float* e_all  = w_all  + (size_t)num_q * 64;         // NV*128
    float* a_all  = e_all  + (size_t)NV * 128;           // NV*128
    float* kf_all = a_all  + (size_t)NV * 128;           // num_q*128
    short* eWt    = (short*)(kf_all + (size_t)num_q * 128);
    short* aWt    = eWt  + 128 * 128;
    short* fWrt   = aWt  + 128 * 128;
    short* fWkt   = fWrt + 128 * 128;
    short* Mkb    = fWkt + 128 * 128;                    // 64*128 bf16
    unsigned short* reads_bf = (unsigned short*)(Mkb + 64 * 128);  // ntok*128 bf16

    prep_kernel<<<5, 128, 0, stream>>>(eW, aW, fW, Mk, eWt, aWt, fWrt, fWkt, Mkb);
    const int nbe = (NV + 63) / 64, nbk = (num_q + 63) / 64;
    veakf_kernel<<<nbe + nbk, 256, 0, stream>>>(v_emb, k_emb, eWt, aWt, fWkt, Mkb,
                                                eb, ab, fb, num_q, nbe,
                                                e_all, a_all, kf_all, w_all);
    scan_kernel<<<Bb * 4, 256, 0, stream>>>(Mv0, qseq, cseq, w_all, e_all, a_all,
                                            num_q, reads_bf);
    out_kernel<<<(ntok + 63) / 64, 256, 0, stream>>>(qseq, reads_bf, fWrt, kf_all,
                                                     pW, pb, ntok, (float*)d_out);
}

// Round 5
// 69.458 us; speedup vs baseline: 3.3209x; 1.1167x over previous
//
#include <hip/hip_runtime.h>
#include <math.h>

// DKVMN forward: B=128, S=200, DK=128, DV=64, NUM_Q=10000
//   prep  : convert weights to bf16 [n][k] (+ Mk straight bf16)
//   veakf : e_all/a_all = act(v_emb@{eW,aW}+b)   [2num_q x 128] (bf16 MFMA)
//           kf_all = k_emb @ fW[128:] + fb,  w_all = softmax(k_emb@Mk^T)
//           B staged in 32KB swizzled LDS, two passes; A direct-to-register
//   scan  : sequential memory update; barrier-free steps, per-chunk reduce
//   out   : p = sigmoid(tanh(reads@fW[:128] + kf_all[q]) @ pW + pb)  (MFMA)

typedef float f32x4 __attribute__((ext_vector_type(4)));
typedef short bf16x8 __attribute__((ext_vector_type(8)));

__device__ __forceinline__ float sigm(float x) { return 1.0f / (1.0f + __expf(-x)); }
__device__ __forceinline__ short f2bf(float x) {
    union { float f; unsigned u; } v; v.f = x;
    return (short)((v.u + 0x7FFFu + ((v.u >> 16) & 1u)) >> 16);   // RNE
}

// ---------------------------------------------------------------------------
// prep: 5 blocks x 256 threads.
// blocks 0-3: dst[n*128+k] = bf16(src[k*128+n]) (transpose). block 4: Mk copy.
// ---------------------------------------------------------------------------
__global__ __launch_bounds__(256) void prep_kernel(
    const float* __restrict__ eW, const float* __restrict__ aW,
    const float* __restrict__ fW, const float* __restrict__ Mk,
    short* __restrict__ eWt, short* __restrict__ aWt,
    short* __restrict__ fWrt, short* __restrict__ fWkt,
    short* __restrict__ Mkb)
{
    const int t = threadIdx.x;
    if (blockIdx.x == 4) {   // Mk [64][128] -> bf16, no transpose
        for (int idx = t; idx < 1024; idx += 256) {
            const int row = idx >> 4, c8 = idx & 15;
            const float4 f0 = *(const float4*)(Mk + row * 128 + c8 * 8);
            const float4 f1 = *(const float4*)(Mk + row * 128 + c8 * 8 + 4);
            bf16x8 v;
            v[0] = f2bf(f0.x); v[1] = f2bf(f0.y); v[2] = f2bf(f0.z); v[3] = f2bf(f0.w);
            v[4] = f2bf(f1.x); v[5] = f2bf(f1.y); v[6] = f2bf(f1.z); v[7] = f2bf(f1.w);
            *(bf16x8*)(Mkb + row * 128 + c8 * 8) = v;
        }
        return;
    }
    const float* src; short* dst;
    switch (blockIdx.x) {
        case 0:  src = eW;             dst = eWt;  break;
        case 1:  src = aW;             dst = aWt;  break;
        case 2:  src = fW;             dst = fWrt; break;
        default: src = fW + 128 * 128; dst = fWkt; break;
    }
    const int n  = t & 127;
    const int kh = (t >> 7) * 64;
    for (int k0 = kh; k0 < kh + 64; k0 += 8) {
        bf16x8 v;
        #pragma unroll
        for (int kk = 0; kk < 8; ++kk) v[kk] = f2bf(src[(k0 + kk) * 128 + n]);
        *(bf16x8*)(dst + n * 128 + k0) = v;
    }
}

// ---------------------------------------------------------------------------
// veakf: 64 vocab rows per block, 4 waves, bf16 MFMA 16x16x32.
// blocks [0,nbe): e/a over v_emb.  blocks [nbe,..): kf + w over k_emb.
// B staged in one 32KB swizzled LDS buffer, two passes (eWt->aWt / fWkt->Mkb).
// A fragments built directly in registers from global.
// ---------------------------------------------------------------------------
__global__ __launch_bounds__(256) void veakf_kernel(
    const float* __restrict__ v_emb, const float* __restrict__ k_emb,
    const short* __restrict__ eWt, const short* __restrict__ aWt,
    const short* __restrict__ fWkt, const short* __restrict__ Mkb,
    const float* __restrict__ eb, const float* __restrict__ ab,
    const float* __restrict__ fb,
    int num_q, int nbe,
    float* __restrict__ e_all, float* __restrict__ a_all,
    float* __restrict__ kf_all, float* __restrict__ w_all)
{
    __shared__ __align__(16) short Bsh[128 * 128];   // 32 KB
    const int t = threadIdx.x;
    const bool ea = ((int)blockIdx.x < nbe);
    const int nrows = ea ? 2 * num_q : num_q;
    const int R0 = (ea ? (int)blockIdx.x : (int)blockIdx.x - nbe) * 64;
    const float* Asrc = ea ? v_emb : k_emb;

    const int wv = t >> 6;
    const int lr = t & 15;
    const int lk = (t & 63) >> 4;
    const int arow = wv * 16 + lr;
    int gr = R0 + arow; if (gr > nrows - 1) gr = nrows - 1;

    // ---- A fragments: global -> registers (issue loads first) ----
    float4 a0[4], a1[4];
    #pragma unroll
    for (int ks = 0; ks < 4; ++ks) {
        const int off = (ks * 4 + lk) * 8;
        a0[ks] = *(const float4*)(Asrc + (size_t)gr * 128 + off);
        a1[ks] = *(const float4*)(Asrc + (size_t)gr * 128 + off + 4);
    }
    // ---- stage B pass-1 table (eWt / fWkt), coalesced, XOR-swizzled ----
    {
        const short* B1 = ea ? eWt : fWkt;
        #pragma unroll
        for (int i = 0; i < 8; ++i) {
            const int c = t + 256 * i;
            const int row = c >> 4, ch = c & 15;
            *(bf16x8*)&Bsh[row * 128 + ((ch ^ (row & 7)) * 8)] =
                *(const bf16x8*)(B1 + row * 128 + ch * 8);
        }
    }
    // convert A to bf16 fragments while B loads land
    bf16x8 af[4];
    #pragma unroll
    for (int ks = 0; ks < 4; ++ks) {
        bf16x8 v;
        v[0] = f2bf(a0[ks].x); v[1] = f2bf(a0[ks].y);
        v[2] = f2bf(a0[ks].z); v[3] = f2bf(a0[ks].w);
        v[4] = f2bf(a1[ks].x); v[5] = f2bf(a1[ks].y);
        v[6] = f2bf(a1[ks].z); v[7] = f2bf(a1[ks].w);
        af[ks] = v;
    }
    __syncthreads();

    // ---- pass 1: e (ea) or kf (kw) ----
    f32x4 acc[8];
    #pragma unroll
    for (int ct = 0; ct < 8; ++ct) acc[ct] = (f32x4)0.f;
    #pragma unroll
    for (int ks = 0; ks < 4; ++ks) {
        const int chunk = ks * 4 + lk;
        #pragma unroll
        for (int ct = 0; ct < 8; ++ct) {
            const int n = ct * 16 + lr;
            const bf16x8 b = *(const bf16x8*)&Bsh[n * 128 + ((chunk ^ (n & 7)) * 8)];
            acc[ct] = __builtin_amdgcn_mfma_f32_16x16x32_bf16(af[ks], b, acc[ct], 0, 0, 0);
        }
    }
    if (ea) {
        #pragma unroll
        for (int ct = 0; ct < 8; ++ct) {
            const int col = ct * 16 + lr;
            const float ebv = eb[col];
            #pragma unroll
            for (int r = 0; r < 4; ++r) {
                const int row = R0 + wv * 16 + lk * 4 + r;
                if (row < nrows)
                    e_all[(size_t)row * 128 + col] = sigm(acc[ct][r] + ebv);
            }
        }
    } else {
        #pragma unroll
        for (int ct = 0; ct < 8; ++ct) {
            const int col = ct * 16 + lr;
            const float fbv = fb[col];
            #pragma unroll
            for (int r = 0; r < 4; ++r) {
                const int row = R0 + wv * 16 + lk * 4 + r;
                if (row < nrows)
                    kf_all[(size_t)row * 128 + col] = acc[ct][r] + fbv;
            }
        }
    }
    __syncthreads();   // pass-1 reads of Bsh complete

    // ---- stage B pass-2 table (aWt / Mkb) ----
    if (ea) {
        #pragma unroll
        for (int i = 0; i < 8; ++i) {
            const int c = t + 256 * i;
            const int row = c >> 4, ch = c & 15;
            *(bf16x8*)&Bsh[row * 128 + ((ch ^ (row & 7)) * 8)] =
                *(const bf16x8*)(aWt + row * 128 + ch * 8);
        }
    } else {
        #pragma unroll
        for (int i = 0; i < 4; ++i) {
            const int c = t + 256 * i;
            const int row = c >> 4, ch = c & 15;
            *(bf16x8*)&Bsh[row * 128 + ((ch ^ (row & 7)) * 8)] =
                *(const bf16x8*)(Mkb + row * 128 + ch * 8);
        }
    }
    __syncthreads();

    // ---- pass 2: a (ea) or w softmax (kw) ----
    if (ea) {
        #pragma unroll
        for (int ct = 0; ct < 8; ++ct) acc[ct] = (f32x4)0.f;
        #pragma unroll
        for (int ks = 0; ks < 4; ++ks) {
            const int chunk = ks * 4 + lk;
            #pragma unroll
            for (int ct = 0; ct < 8; ++ct) {
                const int n = ct * 16 + lr;
                const bf16x8 b = *(const bf16x8*)&Bsh[n * 128 + ((chunk ^ (n & 7)) * 8)];
                acc[ct] = __builtin_amdgcn_mfma_f32_16x16x32_bf16(af[ks], b, acc[ct], 0, 0, 0);
            }
        }
        #pragma unroll
        for (int ct = 0; ct < 8; ++ct) {
            const int col = ct * 16 + lr;
            const float abv = ab[col];
            #pragma unroll
            for (int r = 0; r < 4; ++r) {
                const int row = R0 + wv * 16 + lk * 4 + r;
                if (row < nrows)
                    a_all[(size_t)row * 128 + col] = tanhf(acc[ct][r] + abv);
            }
        }
    } else {
        f32x4 accw[4];
        #pragma unroll
        for (int ct = 0; ct < 4; ++ct) accw[ct] = (f32x4)0.f;
        #pragma unroll
        for (int ks = 0; ks < 4; ++ks) {
            const int chunk = ks * 4 + lk;
            #pragma unroll
            for (int ct = 0; ct < 4; ++ct) {
                const int n = ct * 16 + lr;
                const bf16x8 b = *(const bf16x8*)&Bsh[n * 128 + ((chunk ^ (n & 7)) * 8)];
                accw[ct] = __builtin_amdgcn_mfma_f32_16x16x32_bf16(af[ks], b, accw[ct], 0, 0, 0);
            }
        }
        // softmax over 64 memory slots (4 ct regs x 16 lr lanes)
        #pragma unroll
        for (int r = 0; r < 4; ++r) {
            const float x0 = accw[0][r], x1 = accw[1][r];
            const float x2 = accw[2][r], x3 = accw[3][r];
            float m = fmaxf(fmaxf(x0, x1), fmaxf(x2, x3));
            #pragma unroll
            for (int mk = 1; mk < 16; mk <<= 1) m = fmaxf(m, __shfl_xor(m, mk));
            const float e0 = __expf(x0 - m), e1 = __expf(x1 - m);
            const float e2 = __expf(x2 - m), e3 = __expf(x3 - m);
            float s = (e0 + e1) + (e2 + e3);
            #pragma unroll
            for (int mk = 1; mk < 16; mk <<= 1) s += __shfl_xor(s, mk);
            const float inv = 1.0f / s;
            const int row = R0 + wv * 16 + lk * 4 + r;
            if (row < nrows) {
                float* wr = w_all + (size_t)row * 64 + lr;
                wr[0]  = e0 * inv; wr[16] = e1 * inv;
                wr[32] = e2 * inv; wr[48] = e3 * inv;
            }
        }
    }
}

// ---------------------------------------------------------------------------
// scan: block = (batch, j-quarter of 32), 256 threads = 8 v-groups x 32 j.
// Recurrence is independent per (v,j): NO per-step barrier. Partial reads go
// to double-buffered LDS; one barrier + reduce per 8-step chunk. Gathers
// w/e/a rows from vocab tables one chunk ahead. 512 blocks -> 8 waves/CU.
// ---------------------------------------------------------------------------
__global__ __launch_bounds__(256) void scan_kernel(
    const float* __restrict__ Mv0,
    const int* __restrict__ qseq, const int* __restrict__ cseq,
    const float* __restrict__ w_all, const float* __restrict__ e_all,
    const float* __restrict__ a_all, int num_q,
    unsigned short* __restrict__ reads_bf)
{
    const int t  = threadIdx.x;
    const int j  = t & 31;          // column within quarter
    const int vg = t >> 5;          // v-group: owns slots [vg*8, vg*8+8)
    const int cq = blockIdx.x & 3;
    const int b  = blockIdx.x >> 2;
    const int jg = cq * 32 + j;

    float Mv[8];
    #pragma unroll
    for (int i = 0; i < 8; ++i) Mv[i] = Mv0[(vg * 8 + i) * 128 + jg];

    __shared__ float wb[2][8][64];
    __shared__ float ebuf[2][8][32];
    __shared__ float abuf[2][8][32];
    __shared__ float part[2][8][8][32];   // [buf][step][vg][j]
    __shared__ int sq[200], sx[200];

    if (t < 200) {
        const int q = qseq[b * 200 + t];
        const int c = cseq[b * 200 + t];
        sq[t] = q * 16;                        // float4 row offset in w_all
        sx[t] = (q + num_q * c) * 32 + cq * 8; // float4 offset in e/a quarter
    }
    __syncthreads();

    const float4* w4 = (const float4*)w_all;
    const float4* e4 = (const float4*)e_all;
    const float4* a4 = (const float4*)a_all;

    // chunk 0 gather -> buf 0 (1 float4 per thread)
    float4 rg;
    if (t < 128)      { rg = w4[sq[t >> 4] + (t & 15)];                       ((float4*)wb[0])[t] = rg; }
    else if (t < 192) { const int u = t - 128; rg = e4[sx[u >> 3] + (u & 7)]; ((float4*)ebuf[0])[u] = rg; }
    else              { const int u = t - 192; rg = a4[sx[u >> 3] + (u & 7)]; ((float4*)abuf[0])[u] = rg; }
    __syncthreads();

    int cb = 0, pbuf = 0;
    for (int c = 0; c < 25; ++c) {
        if (c < 24) {   // issue next-chunk gathers (complete under this chunk)
            const int s0 = (c + 1) * 8;
            if (t < 128)      rg = w4[sq[s0 + (t >> 4)] + (t & 15)];
            else if (t < 192) { const int u = t - 128; rg = e4[sx[s0 + (u >> 3)] + (u & 7)]; }
            else              { const int u = t - 192; rg = a4[sx[s0 + (u >> 3)] + (u & 7)]; }
        }
        #pragma unroll
        for (int st = 0; st < 8; ++st) {
            const float e_j = ebuf[cb][st][j];
            const float a_j = abuf[cb][st][j];
            const float* wrow = &wb[cb][st][vg * 8];
            float r0 = 0.f, r1 = 0.f, r2 = 0.f, r3 = 0.f;
            #pragma unroll
            for (int v4i = 0; v4i < 2; ++v4i) {
                const float4 w4v = *(const float4*)&wrow[v4i * 4];  // broadcast
                const int v = v4i * 4;
                r0 = fmaf(w4v.x, Mv[v + 0], r0);
                Mv[v + 0] = fmaf(w4v.x, fmaf(-Mv[v + 0], e_j, a_j), Mv[v + 0]);
                r1 = fmaf(w4v.y, Mv[v + 1], r1);
                Mv[v + 1] = fmaf(w4v.y, fmaf(-Mv[v + 1], e_j, a_j), Mv[v + 1]);
                r2 = fmaf(w4v.z, Mv[v + 2], r2);
                Mv[v + 2] = fmaf(w4v.z, fmaf(-Mv[v + 2], e_j, a_j), Mv[v + 2]);
                r3 = fmaf(w4v.w, Mv[v + 3], r3);
                Mv[v + 3] = fmaf(w4v.w, fmaf(-Mv[v + 3], e_j, a_j), Mv[v + 3]);
            }
            part[pbuf][st][vg][j] = (r0 + r1) + (r2 + r3);
        }
        if (c < 24) {   // stage next chunk (regs -> other buffer)
            if (t < 128)      ((float4*)wb[cb ^ 1])[t] = rg;
            else if (t < 192) ((float4*)ebuf[cb ^ 1])[t - 128] = rg;
            else              ((float4*)abuf[cb ^ 1])[t - 192] = rg;
        }
        __syncthreads();
        // reduce: one (step, j) per thread, sum 8 v-group partials
        {
            const int st = t >> 5, jr = t & 31;
            const float* pp = &part[pbuf][st][0][jr];
            float r = 0.f;
            #pragma unroll
            for (int g = 0; g < 8; ++g) r += pp[g * 32];
            reads_bf[(size_t)b * 200 * 128 + (size_t)(c * 8 + st) * 128 + cq * 32 + jr]
                = (unsigned short)f2bf(r);
        }
        cb ^= 1; pbuf ^= 1;
    }
}

// ---------------------------------------------------------------------------
// out: 64 tokens per block, bf16 MFMA. acc init = kf_all[q] (+fb already in).
// ---------------------------------------------------------------------------
__global__ __launch_bounds__(256) void out_kernel(
    const int* __restrict__ qseq,
    const unsigned short* __restrict__ reads_bf,
    const short* __restrict__ fWrt, const float* __restrict__ kf_all,
    const float* __restrict__ pW, const float* __restrict__ pb,
    int ntok, float* __restrict__ out)
{
    __shared__ __align__(16) short Ash[64 * 128];
    __shared__ int qi[64];
    const int t = threadIdx.x;
    const int R0 = blockIdx.x * 64;
    if (t < 64) { int r = R0 + t; qi[t] = qseq[r < ntok ? r : ntok - 1]; }
    #pragma unroll
    for (int i = 0; i < 4; ++i) {
        const int c = t + 256 * i;
        const int row = c >> 4, ch = c & 15;
        int gr = R0 + row; if (gr > ntok - 1) gr = ntok - 1;
        const bf16x8 v = *(const bf16x8*)(reads_bf + (size_t)gr * 128 + ch * 8);
        *(bf16x8*)&Ash[row * 128 + ((ch ^ (row & 7)) * 8)] = v;
    }
    __syncthreads();

    const int wv = t >> 6;
    const int lr = t & 15;
    const int lk = (t & 63) >> 4;
    const int arow = wv * 16 + lr;

    f32x4 acc[8];
    #pragma unroll
    for (int ct = 0; ct < 8; ++ct) {
        const int col = ct * 16 + lr;
        #pragma unroll
        for (int r = 0; r < 4; ++r) {
            const int q = qi[wv * 16 + lk * 4 + r];
            acc[ct][r] = kf_all[(size_t)q * 128 + col];
        }
    }
    #pragma unroll
    for (int ks = 0; ks < 4; ++ks) {
        const int chunk = ks * 4 + lk;
        const bf16x8 af = *(const bf16x8*)&Ash[arow * 128 + ((chunk ^ (arow & 7)) * 8)];
        const int kb = ks * 32 + lk * 8;
        #pragma unroll
        for (int ct = 0; ct < 8; ++ct) {
            const int n = ct * 16 + lr;
            const bf16x8 bfr = *(const bf16x8*)(fWrt + n * 128 + kb);
            acc[ct] = __builtin_amdgcn_mfma_f32_16x16x32_bf16(af, bfr, acc[ct], 0, 0, 0);
        }
    }
    const float pb0 = pb[0];
    float s0 = 0.f, s1 = 0.f, s2 = 0.f, s3 = 0.f;
    #pragma unroll
    for (int ct = 0; ct < 8; ++ct) {
        const float pw = pW[ct * 16 + lr];
        s0 = fmaf(tanhf(acc[ct][0]), pw, s0);
        s1 = fmaf(tanhf(acc[ct][1]), pw, s1);
        s2 = fmaf(tanhf(acc[ct][2]), pw, s2);
        s3 = fmaf(tanhf(acc[ct][3]), pw, s3);
    }
    #pragma unroll
    for (int off = 1; off < 16; off <<= 1) {
        s0 += __shfl_xor(s0, off);
        s1 += __shfl_xor(s1, off);
        s2 += __shfl_xor(s2, off);
        s3 += __shfl_xor(s3, off);
    }
    if (lr == 0) {
        const int row = R0 + wv * 16 + lk * 4;
        if (row + 0 < ntok) out[row + 0] = sigm(s0 + pb0);
        if (row + 1 < ntok) out[row + 1] = sigm(s1 + pb0);
        if (row + 2 < ntok) out[row + 2] = sigm(s2 + pb0);
        if (row + 3 < ntok) out[row + 3] = sigm(s3 + pb0);
    }
}

// ---------------------------------------------------------------------------
extern "C" void kernel_launch(void* const* d_in, const int* in_sizes, int n_in,
                              void* d_out, int out_size, void* d_ws, size_t ws_size,
                              hipStream_t stream)
{
    const int*   qseq  = (const int*)d_in[0];
    const int*   cseq  = (const int*)d_in[1];
    const float* k_emb = (const float*)d_in[2];
    const float* v_emb = (const float*)d_in[3];
    const float* Mk    = (const float*)d_in[4];
    const float* Mv0   = (const float*)d_in[5];
    const float* fW    = (const float*)d_in[6];
    const float* fb    = (const float*)d_in[7];
    const float* eW    = (const float*)d_in[8];
    const float* eb    = (const float*)d_in[9];
    const float* aW    = (const float*)d_in[10];
    const float* ab    = (const float*)d_in[11];
    const float* pW    = (const float*)d_in[12];
    const float* pb    = (const float*)d_in[13];

    const int num_q = in_sizes[2] / 128;   // 10000
    const int ntok  = in_sizes[0];         // B*S = 25600
    const int Bb    = ntok / 200;          // 128
    const int NV    = 2 * num_q;

    float* ws = (float*)d_ws;
    float* w_all  = ws;                                  // num_q*64
    float* e_all  = w_all  + (size_t)num_q * 64;         // NV*128
    float* a_all  = e_all  + (size_t)NV * 128;           // NV*128
    float* kf_all = a_all  + (size_t)NV * 128;           // num_q*128
    short* eWt    = (short*)(kf_all + (size_t)num_q * 128);
    short* aWt    = eWt  + 128 * 128;
    short* fWrt   = aWt  + 128 * 128;
    short* fWkt   = fWrt + 128 * 128;
    short* Mkb    = fWkt + 128 * 128;                    // 64*128 bf16
    unsigned short* reads_bf = (unsigned short*)(Mkb + 64 * 128);  // ntok*128 bf16

    prep_kernel<<<5, 256, 0, stream>>>(eW, aW, fW, Mk, eWt, aWt, fWrt, fWkt, Mkb);
    const int nbe = (NV + 63) / 64, nbk = (num_q + 63) / 64;
    veakf_kernel<<<nbe + nbk, 256, 0, stream>>>(v_emb, k_emb, eWt, aWt, fWkt, Mkb,
                                                eb, ab, fb, num_q, nbe,
                                                e_all, a_all, kf_all, w_all);
    scan_kernel<<<Bb * 4, 256, 0, stream>>>(Mv0, qseq, cseq, w_all, e_all, a_all,
                                            num_q, reads_bf);
    out_kernel<<<(ntok + 63) / 64, 256, 0, stream>>>(qseq, reads_bf, fWrt, kf_all,
                                                     pW, pb, ntok, (float*)d_out);
}